// Round 5
// baseline (3178.068 us; speedup 1.0000x reference)
//
#include <hip/hip_runtime.h>
#include <hip/hip_fp16.h>
#include <hip/hip_bf16.h>

#define TSTEPS 1019
#define BATCH 8
#define CIN 4
#define LEN 524288
#define COUT 512
#define HID 512
#define KERN 3072
#define CSTRIDE 512
#define KTOT (CIN * KERN)          // 12288
#define MROWS (TSTEPS * BATCH)     // 8152

typedef _Float16 half2_v __attribute__((ext_vector_type(2)));
typedef __attribute__((ext_vector_type(8))) short bf16x8;
typedef __attribute__((ext_vector_type(4))) float f32x4;

#if defined(__has_builtin)
#if __has_builtin(__builtin_amdgcn_fdot2)
#define HAVE_FDOT2 1
#endif
#endif

__device__ __forceinline__ float dot2f(__half2 a, __half2 b, float c) {
#ifdef HAVE_FDOT2
    return __builtin_amdgcn_fdot2(__builtin_bit_cast(half2_v, a),
                                  __builtin_bit_cast(half2_v, b), c, false);
#else
    float2 af = __half22float2(a), bf = __half22float2(b);
    return fmaf(af.y, bf.y, fmaf(af.x, bf.x, c));
#endif
}

struct __align__(16) H2x4 { __half2 x, y, z, w; };

__device__ __forceinline__ short bfc(float x) {
    return (short)__builtin_bit_cast(unsigned short, __float2bfloat16(x));
}

__device__ __forceinline__ void load_lds16(const unsigned short* g, unsigned short* l) {
    __builtin_amdgcn_global_load_lds(
        (const __attribute__((address_space(1))) void*)g,
        (__attribute__((address_space(3))) void*)l, 16, 0, 0);
}

// ---------------------------------------------------------------------------
// fp32 -> bf16 convert (unchanged)
// ---------------------------------------------------------------------------
__global__ __launch_bounds__(256) void f2bf_k(
        const float* __restrict__ a, unsigned short* __restrict__ o, int n4) {
    int i = blockIdx.x * blockDim.x + threadIdx.x;
    int stride = gridDim.x * blockDim.x;
    for (; i < n4; i += stride) {
        float4 f = reinterpret_cast<const float4*>(a)[i];
        ushort4 u;
        u.x = (unsigned short)bfc(f.x); u.y = (unsigned short)bfc(f.y);
        u.z = (unsigned short)bfc(f.z); u.w = (unsigned short)bfc(f.w);
        reinterpret_cast<ushort4*>(o)[i] = u;
    }
}

// ---------------------------------------------------------------------------
// Conv1d implicit GEMM on MFMA (unchanged from round 4)
// ---------------------------------------------------------------------------
__global__ __launch_bounds__(256, 2) void conv_mfma_k(
        const float* __restrict__ in, const unsigned short* __restrict__ wb,
        const float* __restrict__ bias, unsigned short* __restrict__ out) {
    __shared__ unsigned short At[2][128 * 64];
    __shared__ unsigned short Bt[2][128 * 64];
    const int m0 = blockIdx.y * 128;
    const int n0 = blockIdx.x * 128;
    const int tid = threadIdx.x;
    const int w = tid >> 6, l = tid & 63;
    const int wm = w >> 1, wn = w & 1;
    const int fr = l & 15, fq = l >> 4;

    const int ra = tid >> 1, hh = tid & 1;
    int mA = m0 + ra; if (mA > MROWS - 1) mA = MROWS - 1;
    const int tA = mA >> 3, bA = mA & 7;

    f32x4 acc[4][4] = {};
    const int NT = KTOT / 64;

    {
        const float* src = in + (size_t)(bA * CIN + 0) * LEN
                              + (size_t)tA * CSTRIDE + 0 + hh * 32;
        #pragma unroll
        for (int cc = 0; cc < 4; ++cc) {
            float4 f0 = reinterpret_cast<const float4*>(src)[cc * 2];
            float4 f1 = reinterpret_cast<const float4*>(src)[cc * 2 + 1];
            bf16x8 v;
            v[0] = bfc(f0.x); v[1] = bfc(f0.y); v[2] = bfc(f0.z); v[3] = bfc(f0.w);
            v[4] = bfc(f1.x); v[5] = bfc(f1.y); v[6] = bfc(f1.z); v[7] = bfc(f1.w);
            const int c = hh * 4 + cc, s = c ^ (ra & 7);
            *reinterpret_cast<bf16x8*>(&At[0][ra * 64 + s * 8]) = v;
        }
        #pragma unroll
        for (int i = 0; i < 4; ++i) {
            const int rb = w * 32 + i * 8 + (l >> 3);
            const int s = l & 7, c = s ^ (rb & 7);
            load_lds16(wb + (size_t)(n0 + rb) * KTOT + 0 + c * 8,
                       &Bt[0][(w * 32 + i * 8) * 64]);
        }
    }
    __syncthreads();

    int cur = 0;
    for (int t = 0; t < NT; ++t) {
        const int nxt = cur ^ 1;
        float4 fA[8];
        const bool more = (t + 1 < NT);
        if (more) {
            const int k0 = (t + 1) * 64;
            const int ci = k0 / KERN, kr = k0 - ci * KERN;
            const float* src = in + (size_t)(bA * CIN + ci) * LEN
                                  + (size_t)tA * CSTRIDE + kr + hh * 32;
            #pragma unroll
            for (int v = 0; v < 8; ++v)
                fA[v] = reinterpret_cast<const float4*>(src)[v];
            #pragma unroll
            for (int i = 0; i < 4; ++i) {
                const int rb = w * 32 + i * 8 + (l >> 3);
                const int s = l & 7, c = s ^ (rb & 7);
                load_lds16(wb + (size_t)(n0 + rb) * KTOT + k0 + c * 8,
                           &Bt[nxt][(w * 32 + i * 8) * 64]);
            }
        }
        #pragma unroll
        for (int ks = 0; ks < 2; ++ks) {
            bf16x8 af[4], bfg[4];
            #pragma unroll
            for (int mf = 0; mf < 4; ++mf) {
                const int rA = wm * 64 + mf * 16 + fr;
                const int cw = ks * 4 + fq, s = cw ^ (rA & 7);
                af[mf] = *reinterpret_cast<const bf16x8*>(&At[cur][rA * 64 + s * 8]);
            }
            #pragma unroll
            for (int nf = 0; nf < 4; ++nf) {
                const int rB = wn * 64 + nf * 16 + fr;
                const int cw = ks * 4 + fq, s = cw ^ (rB & 7);
                bfg[nf] = *reinterpret_cast<const bf16x8*>(&Bt[cur][rB * 64 + s * 8]);
            }
            #pragma unroll
            for (int mf = 0; mf < 4; ++mf)
                #pragma unroll
                for (int nf = 0; nf < 4; ++nf)
                    acc[mf][nf] = __builtin_amdgcn_mfma_f32_16x16x32_bf16(
                        af[mf], bfg[nf], acc[mf][nf], 0, 0, 0);
        }
        if (more) {
            #pragma unroll
            for (int cc = 0; cc < 4; ++cc) {
                float4 f0 = fA[cc * 2], f1 = fA[cc * 2 + 1];
                bf16x8 v;
                v[0] = bfc(f0.x); v[1] = bfc(f0.y); v[2] = bfc(f0.z); v[3] = bfc(f0.w);
                v[4] = bfc(f1.x); v[5] = bfc(f1.y); v[6] = bfc(f1.z); v[7] = bfc(f1.w);
                const int c = hh * 4 + cc, s = c ^ (ra & 7);
                *reinterpret_cast<bf16x8*>(&At[nxt][ra * 64 + s * 8]) = v;
            }
        }
        __syncthreads();
        cur = nxt;
    }

    #pragma unroll
    for (int nf = 0; nf < 4; ++nf) {
        const int n = n0 + wn * 64 + nf * 16 + fr;
        const float bv = bias[n];
        #pragma unroll
        for (int mf = 0; mf < 4; ++mf) {
            #pragma unroll
            for (int i = 0; i < 4; ++i) {
                const int m = m0 + wm * 64 + mf * 16 + fq * 4 + i;
                if (m < MROWS)
                    out[(size_t)m * COUT + n] =
                        (unsigned short)bfc(acc[mf][nf][i] + bv);
            }
        }
    }
}

// ---------------------------------------------------------------------------
// gi projection MFMA (unchanged from round 4)
// ---------------------------------------------------------------------------
__global__ __launch_bounds__(256, 2) void proj_mfma_k(
        const unsigned short* __restrict__ A, const unsigned short* __restrict__ wb,
        const float* __restrict__ bias, float* __restrict__ out) {
    __shared__ unsigned short At[2][128 * 64];
    __shared__ unsigned short Bt[2][128 * 64];
    const int m0 = blockIdx.y * 128;
    const int n0 = blockIdx.x * 128;
    const int tid = threadIdx.x;
    const int w = tid >> 6, l = tid & 63;
    const int wm = w >> 1, wn = w & 1;
    const int fr = l & 15, fq = l >> 4;

    f32x4 acc[4][4] = {};
    const int NT = COUT / 64;

    auto stage = [&](int buf, int k0) {
        #pragma unroll
        for (int i = 0; i < 4; ++i) {
            const int r = w * 32 + i * 8 + (l >> 3);
            const int s = l & 7, c = s ^ (r & 7);
            int mA = m0 + r; if (mA > MROWS - 1) mA = MROWS - 1;
            load_lds16(A + (size_t)mA * COUT + k0 + c * 8,
                       &At[buf][(w * 32 + i * 8) * 64]);
            load_lds16(wb + (size_t)(n0 + r) * COUT + k0 + c * 8,
                       &Bt[buf][(w * 32 + i * 8) * 64]);
        }
    };

    stage(0, 0);
    __syncthreads();
    int cur = 0;
    for (int t = 0; t < NT; ++t) {
        const int nxt = cur ^ 1;
        if (t + 1 < NT) stage(nxt, (t + 1) * 64);
        #pragma unroll
        for (int ks = 0; ks < 2; ++ks) {
            bf16x8 af[4], bfg[4];
            #pragma unroll
            for (int mf = 0; mf < 4; ++mf) {
                const int rA = wm * 64 + mf * 16 + fr;
                const int cw = ks * 4 + fq, s = cw ^ (rA & 7);
                af[mf] = *reinterpret_cast<const bf16x8*>(&At[cur][rA * 64 + s * 8]);
            }
            #pragma unroll
            for (int nf = 0; nf < 4; ++nf) {
                const int rB = wn * 64 + nf * 16 + fr;
                const int cw = ks * 4 + fq, s = cw ^ (rB & 7);
                bfg[nf] = *reinterpret_cast<const bf16x8*>(&Bt[cur][rB * 64 + s * 8]);
            }
            #pragma unroll
            for (int mf = 0; mf < 4; ++mf)
                #pragma unroll
                for (int nf = 0; nf < 4; ++nf)
                    acc[mf][nf] = __builtin_amdgcn_mfma_f32_16x16x32_bf16(
                        af[mf], bfg[nf], acc[mf][nf], 0, 0, 0);
        }
        __syncthreads();
        cur = nxt;
    }

    #pragma unroll
    for (int nf = 0; nf < 4; ++nf) {
        const int n = n0 + wn * 64 + nf * 16 + fr;
        const float bv = bias[n];
        #pragma unroll
        for (int mf = 0; mf < 4; ++mf) {
            #pragma unroll
            for (int i = 0; i < 4; ++i) {
                const int m = m0 + wm * 64 + mf * 16 + fq * 4 + i;
                if (m < MROWS)
                    out[(size_t)m * 1536 + n] = acc[mf][nf][i] + bv;
            }
        }
    }
}

// ---------------------------------------------------------------------------
// GRU scan, round 5: 4 teams x 8 slice-blocks, 2 batches per team, ping-pong.
// Each block owns 64 h-rows (x3 gates) = 96 weight VGPRs/thread (shared by
// both batches). Half-step: matvec(pb) -> B1 -> gates+publish(pb) ->
// poll(other) -> B2. Each publish->poll gap spans the other batch's compute,
// hiding the MALL round trip. Per batch this is the round-3 proven protocol:
// packed {epoch|2xfp16} words, relaxed agent store/poll, parity double-buffer
// (h_t carries epoch t in buffer t&1; polled epochs >= 1 so memset-0 words
// never match).
// ---------------------------------------------------------------------------
#define MATVEC(PB)                                                            \
    do {                                                                      \
        const H2x4* hv4 = reinterpret_cast<const H2x4*>(&hh2[PB][q * 32]);    \
        float a0 = 0, a1 = 0, a2 = 0, c0 = 0, c1 = 0, c2 = 0;                 \
        _Pragma("unroll")                                                     \
        for (int kk = 0; kk < 8; ++kk) {                                      \
            H2x4 h4 = hv4[kk];                                                \
            a0 = dot2f(wreg[0][4 * kk + 0], h4.x, a0);                        \
            a1 = dot2f(wreg[1][4 * kk + 0], h4.x, a1);                        \
            a2 = dot2f(wreg[2][4 * kk + 0], h4.x, a2);                        \
            c0 = dot2f(wreg[0][4 * kk + 1], h4.y, c0);                        \
            c1 = dot2f(wreg[1][4 * kk + 1], h4.y, c1);                        \
            c2 = dot2f(wreg[2][4 * kk + 1], h4.y, c2);                        \
            a0 = dot2f(wreg[0][4 * kk + 2], h4.z, a0);                        \
            a1 = dot2f(wreg[1][4 * kk + 2], h4.z, a1);                        \
            a2 = dot2f(wreg[2][4 * kk + 2], h4.z, a2);                        \
            c0 = dot2f(wreg[0][4 * kk + 3], h4.w, c0);                        \
            c1 = dot2f(wreg[1][4 * kk + 3], h4.w, c1);                        \
            c2 = dot2f(wreg[2][4 * kk + 3], h4.w, c2);                        \
        }                                                                     \
        p_lds[(0 * 64 + g) * 9 + q] = a0 + c0;                                \
        p_lds[(1 * 64 + g) * 9 + q] = a1 + c1;                                \
        p_lds[(2 * 64 + g) * 9 + q] = a2 + c2;                                \
    } while (0)

#define GATE_PHASE(PB, BB)                                                    \
    do {                                                                      \
        const float* pr = &p_lds[(0 * 64 + tid) * 9];                         \
        const float* pz = &p_lds[(1 * 64 + tid) * 9];                         \
        const float* pn = &p_lds[(2 * 64 + tid) * 9];                         \
        const float ghr = ((pr[0] + pr[1]) + (pr[2] + pr[3]))                 \
                        + ((pr[4] + pr[5]) + (pr[6] + pr[7])) + bhr;          \
        const float ghz = ((pz[0] + pz[1]) + (pz[2] + pz[3]))                 \
                        + ((pz[4] + pz[5]) + (pz[6] + pz[7])) + bhz;          \
        const float ghn = ((pn[0] + pn[1]) + (pn[2] + pn[3]))                 \
                        + ((pn[4] + pn[5]) + (pn[6] + pn[7])) + bhn;          \
        const float r = 1.f / (1.f + __expf(-(gir##PB + ghr)));               \
        const float z = 1.f / (1.f + __expf(-(giz##PB + ghz)));               \
        const float nx = gin##PB + r * ghn;                                   \
        const float n = 1.f - 2.f / (__expf(2.f * nx) + 1.f);                 \
        const float hnew = (1.f - z) * n + z * hprev##PB;                     \
        hprev##PB = hnew;                                                     \
        const float hother = __shfl_xor(hnew, 1);                             \
        if (!(tid & 1)) {                                                     \
            __half2 h2 = __halves2half2(__float2half(hnew),                   \
                                        __float2half(hother));                \
            unsigned long long v =                                            \
                ((unsigned long long)(unsigned)(t + 1) << 32) |               \
                (unsigned long long)__builtin_bit_cast(unsigned, h2);         \
            __hip_atomic_store(                                               \
                h_ex + (size_t)(((t + 1) & 1) * BATCH + BB) * 256             \
                     + isl * 32 + (tid >> 1),                                 \
                v, __ATOMIC_RELAXED, __HIP_MEMORY_SCOPE_AGENT);               \
        }                                                                     \
        out[(size_t)(t * BATCH + BB) * HID + j] = hnew;                       \
        const int tn = (t + 1 < TSTEPS) ? t + 1 : t;                          \
        const float* gp = gi + (size_t)(tn * BATCH + BB) * 1536 + j;          \
        gir##PB = gp[0]; giz##PB = gp[512]; gin##PB = gp[1024];               \
    } while (0)

#define POLL_PHASE(PB, BB, EP)                                                \
    do {                                                                      \
        unsigned long long* src = h_ex                                        \
            + (size_t)(((EP) & 1) * BATCH + BB) * 256 + tid;                  \
        unsigned long long v;                                                 \
        do {                                                                  \
            v = __hip_atomic_load(src, __ATOMIC_RELAXED,                      \
                                  __HIP_MEMORY_SCOPE_AGENT);                  \
        } while ((unsigned)(v >> 32) != (unsigned)(EP));                      \
        hh2[PB][tid] = __builtin_bit_cast(__half2, (unsigned)(v & 0xffffffffu)); \
    } while (0)

__global__ __launch_bounds__(512, 1) void gru_scan_k(
        const float* __restrict__ gi, const float* __restrict__ w_hh,
        const float* __restrict__ b_hh, const float* __restrict__ hidden,
        float* __restrict__ out, unsigned long long* __restrict__ h_ex) {
    const int bid  = blockIdx.x;
    const int team = bid >> 3;           // 4 teams
    const int isl  = bid & 7;            // slice 0..7 within team
    const int b0 = team * 2, b1 = team * 2 + 1;
    const int tid = threadIdx.x;
    const int q = tid >> 6;              // k-octant 0..7 (wave-uniform)
    const int g = tid & 63;              // row-in-slice
    const int j = isl * 64 + g;          // owned h row

    __shared__ __align__(16) __half2 hh2[2][256];   // h per batch as fp16 pairs
    __shared__ float p_lds[3 * 64 * 9];             // partials, stride 9

    // w_hh fragment: 3 gates x 64 k as fp16 -> 96 VGPRs/thread.
    __half2 wreg[3][32];
    #pragma unroll
    for (int m = 0; m < 3; ++m) {
        const float* wp = w_hh + (size_t)(j + m * 512) * HID + q * 64;
        #pragma unroll
        for (int kk = 0; kk < 16; ++kk) {
            float4 v = reinterpret_cast<const float4*>(wp)[kk];
            wreg[m][2 * kk]     = __halves2half2(__float2half_rn(v.x), __float2half_rn(v.y));
            wreg[m][2 * kk + 1] = __halves2half2(__float2half_rn(v.z), __float2half_rn(v.w));
        }
    }

    float bhr = 0.f, bhz = 0.f, bhn = 0.f;
    float hprev0 = 0.f, hprev1 = 0.f;
    float gir0 = 0.f, giz0 = 0.f, gin0 = 0.f;
    float gir1 = 0.f, giz1 = 0.f, gin1 = 0.f;
    if (tid < 64) {
        bhr = b_hh[j]; bhz = b_hh[j + 512]; bhn = b_hh[j + 1024];
        hprev0 = hidden[b0 * HID + j];
        hprev1 = hidden[b1 * HID + j];
        gir0 = gi[(size_t)b0 * 1536 + j];
        giz0 = gi[(size_t)b0 * 1536 + j + 512];
        gin0 = gi[(size_t)b0 * 1536 + j + 1024];
        gir1 = gi[(size_t)b1 * 1536 + j];
        giz1 = gi[(size_t)b1 * 1536 + j + 512];
        gin1 = gi[(size_t)b1 * 1536 + j + 1024];
    }
    if (tid < 256) {
        hh2[0][tid] = __halves2half2(__float2half(hidden[b0 * HID + 2 * tid]),
                                     __float2half(hidden[b0 * HID + 2 * tid + 1]));
        hh2[1][tid] = __halves2half2(__float2half(hidden[b1 * HID + 2 * tid]),
                                     __float2half(hidden[b1 * HID + 2 * tid + 1]));
    }
    __syncthreads();

    for (int t = 0; t < TSTEPS; ++t) {
        // ---- half A: advance b0 to t+1 ----
        MATVEC(0);
        __syncthreads();                                   // B1a
        if (tid < 64) GATE_PHASE(0, b0);
        if (t > 0 && tid < 256) POLL_PHASE(1, b1, t);      // h_t(b1), gap ~= half-step
        __syncthreads();                                   // B2a
        // ---- half B: advance b1 to t+1 ----
        MATVEC(1);
        __syncthreads();                                   // B1b
        if (tid < 64) GATE_PHASE(1, b1);
        if (t + 1 < TSTEPS && tid < 256) POLL_PHASE(0, b0, t + 1);
        __syncthreads();                                   // B2b
    }
    if (tid < 64) {
        out[(size_t)TSTEPS * BATCH * HID + b0 * HID + j] = hprev0;
        out[(size_t)TSTEPS * BATCH * HID + b1 * HID + j] = hprev1;
    }
}

extern "C" void kernel_launch(void* const* d_in, const int* in_sizes, int n_in,
                              void* d_out, int out_size, void* d_ws, size_t ws_size,
                              hipStream_t stream) {
    (void)in_sizes; (void)n_in; (void)out_size; (void)ws_size;
    const float* input  = (const float*)d_in[0];
    const float* hidden = (const float*)d_in[1];
    const float* conv_w = (const float*)d_in[2];
    const float* conv_b = (const float*)d_in[3];
    const float* w_ih   = (const float*)d_in[4];
    const float* w_hh   = (const float*)d_in[5];
    const float* b_ih   = (const float*)d_in[6];
    const float* b_hh   = (const float*)d_in[7];
    float* out = (float*)d_out;

    char* ws = (char*)d_ws;
    float*          gi       = (float*)ws;                          // 50,085,888 B
    unsigned short* conv_out = (unsigned short*)(ws + 50085888);    //  8,347,648 B
    unsigned short* w_bf     = (unsigned short*)(ws + 58433536);    // 12,582,912 B
    unsigned short* wih_bf   = (unsigned short*)(ws + 71016448);    //  1,572,864 B
    unsigned long long* h_ex = (unsigned long long*)(ws + 72589312);//     32,768 B

    f2bf_k<<<2048, 256, 0, stream>>>(conv_w, w_bf, KTOT * COUT / 4);
    f2bf_k<<<768, 256, 0, stream>>>(w_ih, wih_bf, 1536 * COUT / 4);

    dim3 cgrid(4, 64);
    conv_mfma_k<<<cgrid, 256, 0, stream>>>(input, w_bf, conv_b, conv_out);

    dim3 pgrid(12, 64);
    proj_mfma_k<<<pgrid, 256, 0, stream>>>(conv_out, wih_bf, b_ih, gi);

    // reset exchange epochs each launch (replays don't re-poison d_ws)
    hipMemsetAsync(h_ex, 0, 32768, stream);

    gru_scan_k<<<32, 512, 0, stream>>>(gi, w_hh, b_hh, hidden, out, h_ex);
}

// Round 6
// 2872.215 us; speedup vs baseline: 1.1065x; 1.1065x over previous
//
#include <hip/hip_runtime.h>
#include <hip/hip_fp16.h>
#include <hip/hip_bf16.h>

#define TSTEPS 1019
#define BATCH 8
#define CIN 4
#define LEN 524288
#define COUT 512
#define HID 512
#define KERN 3072
#define CSTRIDE 512
#define KTOT (CIN * KERN)          // 12288
#define MROWS (TSTEPS * BATCH)     // 8152

typedef _Float16 half2_v __attribute__((ext_vector_type(2)));
typedef __attribute__((ext_vector_type(8))) short bf16x8;
typedef __attribute__((ext_vector_type(4))) float f32x4;

#if defined(__has_builtin)
#if __has_builtin(__builtin_amdgcn_fdot2)
#define HAVE_FDOT2 1
#endif
#endif

__device__ __forceinline__ float dot2f(__half2 a, __half2 b, float c) {
#ifdef HAVE_FDOT2
    return __builtin_amdgcn_fdot2(__builtin_bit_cast(half2_v, a),
                                  __builtin_bit_cast(half2_v, b), c, false);
#else
    float2 af = __half22float2(a), bf = __half22float2(b);
    return fmaf(af.y, bf.y, fmaf(af.x, bf.x, c));
#endif
}

struct __align__(16) H2x4 { __half2 x, y, z, w; };

__device__ __forceinline__ short bfc(float x) {
    return (short)__builtin_bit_cast(unsigned short, __float2bfloat16(x));
}

__device__ __forceinline__ void load_lds16(const unsigned short* g, unsigned short* l) {
    __builtin_amdgcn_global_load_lds(
        (const __attribute__((address_space(1))) void*)g,
        (__attribute__((address_space(3))) void*)l, 16, 0, 0);
}

// L1-bypassing, L2-served 8B load (sc0). Used for the same-XCD fast path.
__device__ __forceinline__ unsigned long long load_fast(
        const unsigned long long* p) {
    unsigned long long v;
    asm volatile("global_load_dwordx2 %0, %1, off sc0\n\t"
                 "s_waitcnt vmcnt(0)"
                 : "=v"(v) : "v"(p) : "memory");
    return v;
}

// ---------------------------------------------------------------------------
// fp32 -> bf16 convert (unchanged)
// ---------------------------------------------------------------------------
__global__ __launch_bounds__(256) void f2bf_k(
        const float* __restrict__ a, unsigned short* __restrict__ o, int n4) {
    int i = blockIdx.x * blockDim.x + threadIdx.x;
    int stride = gridDim.x * blockDim.x;
    for (; i < n4; i += stride) {
        float4 f = reinterpret_cast<const float4*>(a)[i];
        ushort4 u;
        u.x = (unsigned short)bfc(f.x); u.y = (unsigned short)bfc(f.y);
        u.z = (unsigned short)bfc(f.z); u.w = (unsigned short)bfc(f.w);
        reinterpret_cast<ushort4*>(o)[i] = u;
    }
}

// ---------------------------------------------------------------------------
// Conv1d implicit GEMM on MFMA (unchanged from round 4)
// ---------------------------------------------------------------------------
__global__ __launch_bounds__(256, 2) void conv_mfma_k(
        const float* __restrict__ in, const unsigned short* __restrict__ wb,
        const float* __restrict__ bias, unsigned short* __restrict__ out) {
    __shared__ unsigned short At[2][128 * 64];
    __shared__ unsigned short Bt[2][128 * 64];
    const int m0 = blockIdx.y * 128;
    const int n0 = blockIdx.x * 128;
    const int tid = threadIdx.x;
    const int w = tid >> 6, l = tid & 63;
    const int wm = w >> 1, wn = w & 1;
    const int fr = l & 15, fq = l >> 4;

    const int ra = tid >> 1, hh = tid & 1;
    int mA = m0 + ra; if (mA > MROWS - 1) mA = MROWS - 1;
    const int tA = mA >> 3, bA = mA & 7;

    f32x4 acc[4][4] = {};
    const int NT = KTOT / 64;

    {
        const float* src = in + (size_t)(bA * CIN + 0) * LEN
                              + (size_t)tA * CSTRIDE + 0 + hh * 32;
        #pragma unroll
        for (int cc = 0; cc < 4; ++cc) {
            float4 f0 = reinterpret_cast<const float4*>(src)[cc * 2];
            float4 f1 = reinterpret_cast<const float4*>(src)[cc * 2 + 1];
            bf16x8 v;
            v[0] = bfc(f0.x); v[1] = bfc(f0.y); v[2] = bfc(f0.z); v[3] = bfc(f0.w);
            v[4] = bfc(f1.x); v[5] = bfc(f1.y); v[6] = bfc(f1.z); v[7] = bfc(f1.w);
            const int c = hh * 4 + cc, s = c ^ (ra & 7);
            *reinterpret_cast<bf16x8*>(&At[0][ra * 64 + s * 8]) = v;
        }
        #pragma unroll
        for (int i = 0; i < 4; ++i) {
            const int rb = w * 32 + i * 8 + (l >> 3);
            const int s = l & 7, c = s ^ (rb & 7);
            load_lds16(wb + (size_t)(n0 + rb) * KTOT + 0 + c * 8,
                       &Bt[0][(w * 32 + i * 8) * 64]);
        }
    }
    __syncthreads();

    int cur = 0;
    for (int t = 0; t < NT; ++t) {
        const int nxt = cur ^ 1;
        float4 fA[8];
        const bool more = (t + 1 < NT);
        if (more) {
            const int k0 = (t + 1) * 64;
            const int ci = k0 / KERN, kr = k0 - ci * KERN;
            const float* src = in + (size_t)(bA * CIN + ci) * LEN
                                  + (size_t)tA * CSTRIDE + kr + hh * 32;
            #pragma unroll
            for (int v = 0; v < 8; ++v)
                fA[v] = reinterpret_cast<const float4*>(src)[v];
            #pragma unroll
            for (int i = 0; i < 4; ++i) {
                const int rb = w * 32 + i * 8 + (l >> 3);
                const int s = l & 7, c = s ^ (rb & 7);
                load_lds16(wb + (size_t)(n0 + rb) * KTOT + k0 + c * 8,
                           &Bt[nxt][(w * 32 + i * 8) * 64]);
            }
        }
        #pragma unroll
        for (int ks = 0; ks < 2; ++ks) {
            bf16x8 af[4], bfg[4];
            #pragma unroll
            for (int mf = 0; mf < 4; ++mf) {
                const int rA = wm * 64 + mf * 16 + fr;
                const int cw = ks * 4 + fq, s = cw ^ (rA & 7);
                af[mf] = *reinterpret_cast<const bf16x8*>(&At[cur][rA * 64 + s * 8]);
            }
            #pragma unroll
            for (int nf = 0; nf < 4; ++nf) {
                const int rB = wn * 64 + nf * 16 + fr;
                const int cw = ks * 4 + fq, s = cw ^ (rB & 7);
                bfg[nf] = *reinterpret_cast<const bf16x8*>(&Bt[cur][rB * 64 + s * 8]);
            }
            #pragma unroll
            for (int mf = 0; mf < 4; ++mf)
                #pragma unroll
                for (int nf = 0; nf < 4; ++nf)
                    acc[mf][nf] = __builtin_amdgcn_mfma_f32_16x16x32_bf16(
                        af[mf], bfg[nf], acc[mf][nf], 0, 0, 0);
        }
        if (more) {
            #pragma unroll
            for (int cc = 0; cc < 4; ++cc) {
                float4 f0 = fA[cc * 2], f1 = fA[cc * 2 + 1];
                bf16x8 v;
                v[0] = bfc(f0.x); v[1] = bfc(f0.y); v[2] = bfc(f0.z); v[3] = bfc(f0.w);
                v[4] = bfc(f1.x); v[5] = bfc(f1.y); v[6] = bfc(f1.z); v[7] = bfc(f1.w);
                const int c = hh * 4 + cc, s = c ^ (ra & 7);
                *reinterpret_cast<bf16x8*>(&At[nxt][ra * 64 + s * 8]) = v;
            }
        }
        __syncthreads();
        cur = nxt;
    }

    #pragma unroll
    for (int nf = 0; nf < 4; ++nf) {
        const int n = n0 + wn * 64 + nf * 16 + fr;
        const float bv = bias[n];
        #pragma unroll
        for (int mf = 0; mf < 4; ++mf) {
            #pragma unroll
            for (int i = 0; i < 4; ++i) {
                const int m = m0 + wm * 64 + mf * 16 + fq * 4 + i;
                if (m < MROWS)
                    out[(size_t)m * COUT + n] =
                        (unsigned short)bfc(acc[mf][nf][i] + bv);
            }
        }
    }
}

// ---------------------------------------------------------------------------
// gi projection MFMA (unchanged from round 4)
// ---------------------------------------------------------------------------
__global__ __launch_bounds__(256, 2) void proj_mfma_k(
        const unsigned short* __restrict__ A, const unsigned short* __restrict__ wb,
        const float* __restrict__ bias, float* __restrict__ out) {
    __shared__ unsigned short At[2][128 * 64];
    __shared__ unsigned short Bt[2][128 * 64];
    const int m0 = blockIdx.y * 128;
    const int n0 = blockIdx.x * 128;
    const int tid = threadIdx.x;
    const int w = tid >> 6, l = tid & 63;
    const int wm = w >> 1, wn = w & 1;
    const int fr = l & 15, fq = l >> 4;

    f32x4 acc[4][4] = {};
    const int NT = COUT / 64;

    auto stage = [&](int buf, int k0) {
        #pragma unroll
        for (int i = 0; i < 4; ++i) {
            const int r = w * 32 + i * 8 + (l >> 3);
            const int s = l & 7, c = s ^ (r & 7);
            int mA = m0 + r; if (mA > MROWS - 1) mA = MROWS - 1;
            load_lds16(A + (size_t)mA * COUT + k0 + c * 8,
                       &At[buf][(w * 32 + i * 8) * 64]);
            load_lds16(wb + (size_t)(n0 + r) * COUT + k0 + c * 8,
                       &Bt[buf][(w * 32 + i * 8) * 64]);
        }
    };

    stage(0, 0);
    __syncthreads();
    int cur = 0;
    for (int t = 0; t < NT; ++t) {
        const int nxt = cur ^ 1;
        if (t + 1 < NT) stage(nxt, (t + 1) * 64);
        #pragma unroll
        for (int ks = 0; ks < 2; ++ks) {
            bf16x8 af[4], bfg[4];
            #pragma unroll
            for (int mf = 0; mf < 4; ++mf) {
                const int rA = wm * 64 + mf * 16 + fr;
                const int cw = ks * 4 + fq, s = cw ^ (rA & 7);
                af[mf] = *reinterpret_cast<const bf16x8*>(&At[cur][rA * 64 + s * 8]);
            }
            #pragma unroll
            for (int nf = 0; nf < 4; ++nf) {
                const int rB = wn * 64 + nf * 16 + fr;
                const int cw = ks * 4 + fq, s = cw ^ (rB & 7);
                bfg[nf] = *reinterpret_cast<const bf16x8*>(&Bt[cur][rB * 64 + s * 8]);
            }
            #pragma unroll
            for (int mf = 0; mf < 4; ++mf)
                #pragma unroll
                for (int nf = 0; nf < 4; ++nf)
                    acc[mf][nf] = __builtin_amdgcn_mfma_f32_16x16x32_bf16(
                        af[mf], bfg[nf], acc[mf][nf], 0, 0, 0);
        }
        __syncthreads();
        cur = nxt;
    }

    #pragma unroll
    for (int nf = 0; nf < 4; ++nf) {
        const int n = n0 + wn * 64 + nf * 16 + fr;
        const float bv = bias[n];
        #pragma unroll
        for (int mf = 0; mf < 4; ++mf) {
            #pragma unroll
            for (int i = 0; i < 4; ++i) {
                const int m = m0 + wm * 64 + mf * 16 + fq * 4 + i;
                if (m < MROWS)
                    out[(size_t)m * 1536 + n] = acc[mf][nf][i] + bv;
            }
        }
    }
}

// ---------------------------------------------------------------------------
// GRU scan, round 6. Round-4 topology (8 teams x 4 slice-blocks, b=bid&7 so a
// team's blocks land on one XCD under round-robin dispatch — perf heuristic
// only). New step structure:
//  - wave-local matvec: wave owns 16 rows, lane=(row,kq); k-reduce via 2
//    shfl_xor. No p_lds, no reduce barrier.
//  - hh2 double-buffered by parity -> ONE barrier per step (a thread writes
//    parity p only after the barrier every reader of parity p must also pass).
//  - dual-path exchange: per packed {epoch:32|2xfp16:32} word, producer does
//    a plain store (write-through to its XCD L2) AND the proven agent-scope
//    store (MALL). Consumer polls the L2 copy via sc0 load (L1 bypass);
//    after N spins falls back to the agent-scope word, which is always
//    eventually visible -> correct under ANY block->XCD mapping, fast when
//    the team shares an XCD. Deadlock-freedom = round-3 proof (parity
//    double-buffer + exact-epoch match).
// ---------------------------------------------------------------------------
__global__ __launch_bounds__(512, 1) void gru_scan_k(
        const float* __restrict__ gi, const float* __restrict__ w_hh,
        const float* __restrict__ b_hh, const float* __restrict__ hidden,
        float* __restrict__ out, unsigned long long* __restrict__ h_ex) {
    const int bid = blockIdx.x;
    const int b   = bid & 7;           // batch / team
    const int isl = bid >> 3;          // slice 0..3
    const int tid = threadIdx.x;
    const int wv  = tid >> 6;          // wave 0..7
    const int l   = tid & 63;
    const int r   = l & 15;            // row within wave's 16
    const int kq  = l >> 4;            // k-quarter 0..3
    const int j   = isl * 128 + wv * 16 + r;   // owned h row (same for all kq)

    __shared__ __align__(16) __half2 hh2[2][256];   // parity-double-buffered h

    unsigned long long* hfast = h_ex;               // [2][8][256] L2 fast copy
    unsigned long long* hslow = h_ex + 4096;        // [2][8][256] MALL copy

    // weights: 3 gates x 128 k (quarter kq) of row j -> 192 half2 VGPRs
    __half2 wreg[3][64];
    #pragma unroll
    for (int m = 0; m < 3; ++m) {
        const float* wp = w_hh + (size_t)(j + m * 512) * HID + kq * 128;
        #pragma unroll
        for (int kk = 0; kk < 32; ++kk) {
            float4 v = reinterpret_cast<const float4*>(wp)[kk];
            wreg[m][2 * kk]     = __halves2half2(__float2half_rn(v.x), __float2half_rn(v.y));
            wreg[m][2 * kk + 1] = __halves2half2(__float2half_rn(v.z), __float2half_rn(v.w));
        }
    }

    const float bhr = b_hh[j], bhz = b_hh[j + 512], bhn = b_hh[j + 1024];
    float hprev = hidden[b * HID + j];
    float gir = gi[(size_t)b * 1536 + j];
    float giz = gi[(size_t)b * 1536 + j + 512];
    float gin = gi[(size_t)b * 1536 + j + 1024];

    if (tid < 256)
        hh2[0][tid] = __halves2half2(__float2half(hidden[b * HID + 2 * tid]),
                                     __float2half(hidden[b * HID + 2 * tid + 1]));
    __syncthreads();

    for (int t = 0; t < TSTEPS; ++t) {
        const bool more = (t + 1 < TSTEPS);
        // prefetch gi[t+1] (consumed next iteration; hides under matvec+poll)
        float ngr = 0.f, ngz = 0.f, ngn = 0.f;
        if (more) {
            const float* gp = gi + (size_t)((t + 1) * BATCH + b) * 1536 + j;
            ngr = gp[0]; ngz = gp[512]; ngn = gp[1024];
        }
        // matvec over own k-quarter: 192 dot2, 6 independent chains
        const H2x4* hv4 = reinterpret_cast<const H2x4*>(&hh2[t & 1][0]) + kq * 16;
        float a0 = 0, a1 = 0, a2 = 0, c0 = 0, c1 = 0, c2 = 0;
        #pragma unroll
        for (int kk = 0; kk < 16; ++kk) {
            H2x4 h4 = hv4[kk];
            a0 = dot2f(wreg[0][4 * kk + 0], h4.x, a0);
            a1 = dot2f(wreg[1][4 * kk + 0], h4.x, a1);
            a2 = dot2f(wreg[2][4 * kk + 0], h4.x, a2);
            c0 = dot2f(wreg[0][4 * kk + 1], h4.y, c0);
            c1 = dot2f(wreg[1][4 * kk + 1], h4.y, c1);
            c2 = dot2f(wreg[2][4 * kk + 1], h4.y, c2);
            a0 = dot2f(wreg[0][4 * kk + 2], h4.z, a0);
            a1 = dot2f(wreg[1][4 * kk + 2], h4.z, a1);
            a2 = dot2f(wreg[2][4 * kk + 2], h4.z, a2);
            c0 = dot2f(wreg[0][4 * kk + 3], h4.w, c0);
            c1 = dot2f(wreg[1][4 * kk + 3], h4.w, c1);
            c2 = dot2f(wreg[2][4 * kk + 3], h4.w, c2);
        }
        // k-reduce across the 4 kq lanes (all lanes end with the full sums)
        float ghr = a0 + c0, ghz = a1 + c1, ghn = a2 + c2;
        ghr += __shfl_xor(ghr, 16); ghr += __shfl_xor(ghr, 32);
        ghz += __shfl_xor(ghz, 16); ghz += __shfl_xor(ghz, 32);
        ghn += __shfl_xor(ghn, 16); ghn += __shfl_xor(ghn, 32);
        // gates (computed redundantly in all 4 kq copies; no divergence)
        const float rr = 1.f / (1.f + __expf(-(gir + ghr + bhr)));
        const float zz = 1.f / (1.f + __expf(-(giz + ghz + bhz)));
        const float nx = gin + rr * (ghn + bhn);
        const float nn = 1.f - 2.f / (__expf(2.f * nx) + 1.f);   // tanh
        const float hnew = (1.f - zz) * nn + zz * hprev;
        hprev = hnew;
        gir = ngr; giz = ngz; gin = ngn;
        const float hother = __shfl_xor(hnew, 1);   // pair partner (all lanes)

        if (kq == 0) {
            out[(size_t)(t * BATCH + b) * HID + j] = hnew;
            if (more && !(r & 1)) {
                const __half2 h2 = __halves2half2(__float2half(hnew),
                                                  __float2half(hother));
                const unsigned pay = __builtin_bit_cast(unsigned, h2);
                const unsigned long long v =
                    ((unsigned long long)(unsigned)(t + 1) << 32) |
                    (unsigned long long)pay;
                const size_t idx =
                    (size_t)(((t + 1) & 1) * BATCH + b) * 256 + (j >> 1);
                hfast[idx] = v;                                   // L2 fast copy
                __hip_atomic_store(&hslow[idx], v, __ATOMIC_RELAXED,
                                   __HIP_MEMORY_SCOPE_AGENT);     // authoritative
                hh2[(t + 1) & 1][j >> 1] = h2;                    // own slice local
            }
        }
        if (!more) break;

        // poll the 192 remote words; fast path first, sticky-free fallback
        if (tid < 192) {
            const int word = tid + ((tid >= isl * 64) ? 64 : 0);
            const size_t idx =
                (size_t)(((t + 1) & 1) * BATCH + b) * 256 + word;
            const int spins = (t < 2) ? 1024 : 8;   // absorb launch skew at start
            unsigned long long v; bool got = false;
            for (int it = 0; it < spins; ++it) {
                v = load_fast(&hfast[idx]);
                if ((unsigned)(v >> 32) == (unsigned)(t + 1)) { got = true; break; }
            }
            if (!got) {
                do {
                    v = __hip_atomic_load(&hslow[idx], __ATOMIC_RELAXED,
                                          __HIP_MEMORY_SCOPE_AGENT);
                } while ((unsigned)(v >> 32) != (unsigned)(t + 1));
            }
            hh2[(t + 1) & 1][word] =
                __builtin_bit_cast(__half2, (unsigned)(v & 0xffffffffu));
        }
        __syncthreads();   // single barrier: writes to parity p done before reads
    }
    if (kq == 0)
        out[(size_t)TSTEPS * BATCH * HID + b * HID + j] = hprev;
}

extern "C" void kernel_launch(void* const* d_in, const int* in_sizes, int n_in,
                              void* d_out, int out_size, void* d_ws, size_t ws_size,
                              hipStream_t stream) {
    (void)in_sizes; (void)n_in; (void)out_size; (void)ws_size;
    const float* input  = (const float*)d_in[0];
    const float* hidden = (const float*)d_in[1];
    const float* conv_w = (const float*)d_in[2];
    const float* conv_b = (const float*)d_in[3];
    const float* w_ih   = (const float*)d_in[4];
    const float* w_hh   = (const float*)d_in[5];
    const float* b_ih   = (const float*)d_in[6];
    const float* b_hh   = (const float*)d_in[7];
    float* out = (float*)d_out;

    char* ws = (char*)d_ws;
    float*          gi       = (float*)ws;                          // 50,085,888 B
    unsigned short* conv_out = (unsigned short*)(ws + 50085888);    //  8,347,648 B
    unsigned short* w_bf     = (unsigned short*)(ws + 58433536);    // 12,582,912 B
    unsigned short* wih_bf   = (unsigned short*)(ws + 71016448);    //  1,572,864 B
    unsigned long long* h_ex = (unsigned long long*)(ws + 72589312);//     65,536 B

    f2bf_k<<<2048, 256, 0, stream>>>(conv_w, w_bf, KTOT * COUT / 4);
    f2bf_k<<<768, 256, 0, stream>>>(w_ih, wih_bf, 1536 * COUT / 4);

    dim3 cgrid(4, 64);
    conv_mfma_k<<<cgrid, 256, 0, stream>>>(input, w_bf, conv_b, conv_out);

    dim3 pgrid(12, 64);
    proj_mfma_k<<<pgrid, 256, 0, stream>>>(conv_out, wih_bf, b_ih, gi);

    // reset exchange epochs each launch (replays don't re-poison d_ws)
    hipMemsetAsync(h_ex, 0, 65536, stream);

    gru_scan_k<<<32, 512, 0, stream>>>(gi, w_hh, b_hh, hidden, out, h_ex);
}

// Round 7
// 2843.953 us; speedup vs baseline: 1.1175x; 1.0099x over previous
//
#include <hip/hip_runtime.h>
#include <hip/hip_fp16.h>
#include <hip/hip_bf16.h>

#define TSTEPS 1019
#define BATCH 8
#define CIN 4
#define LEN 524288
#define COUT 512
#define HID 512
#define KERN 3072
#define CSTRIDE 512
#define KTOT (CIN * KERN)          // 12288
#define MROWS (TSTEPS * BATCH)     // 8152

typedef _Float16 half2_v __attribute__((ext_vector_type(2)));
typedef __attribute__((ext_vector_type(8))) short bf16x8;
typedef __attribute__((ext_vector_type(4))) float f32x4;

#if defined(__has_builtin)
#if __has_builtin(__builtin_amdgcn_fdot2)
#define HAVE_FDOT2 1
#endif
#endif

__device__ __forceinline__ float dot2f(__half2 a, __half2 b, float c) {
#ifdef HAVE_FDOT2
    return __builtin_amdgcn_fdot2(__builtin_bit_cast(half2_v, a),
                                  __builtin_bit_cast(half2_v, b), c, false);
#else
    float2 af = __half22float2(a), bf = __half22float2(b);
    return fmaf(af.y, bf.y, fmaf(af.x, bf.x, c));
#endif
}

struct __align__(16) H2x4 { __half2 x, y, z, w; };

__device__ __forceinline__ short bfc(float x) {
    return (short)__builtin_bit_cast(unsigned short, __float2bfloat16(x));
}

__device__ __forceinline__ void load_lds16(const unsigned short* g, unsigned short* l) {
    __builtin_amdgcn_global_load_lds(
        (const __attribute__((address_space(1))) void*)g,
        (__attribute__((address_space(3))) void*)l, 16, 0, 0);
}

// ---------------------------------------------------------------------------
// fp32 -> bf16 convert (unchanged)
// ---------------------------------------------------------------------------
__global__ __launch_bounds__(256) void f2bf_k(
        const float* __restrict__ a, unsigned short* __restrict__ o, int n4) {
    int i = blockIdx.x * blockDim.x + threadIdx.x;
    int stride = gridDim.x * blockDim.x;
    for (; i < n4; i += stride) {
        float4 f = reinterpret_cast<const float4*>(a)[i];
        ushort4 u;
        u.x = (unsigned short)bfc(f.x); u.y = (unsigned short)bfc(f.y);
        u.z = (unsigned short)bfc(f.z); u.w = (unsigned short)bfc(f.w);
        reinterpret_cast<ushort4*>(o)[i] = u;
    }
}

// ---------------------------------------------------------------------------
// Conv1d implicit GEMM on MFMA (unchanged from round 4)
// ---------------------------------------------------------------------------
__global__ __launch_bounds__(256, 2) void conv_mfma_k(
        const float* __restrict__ in, const unsigned short* __restrict__ wb,
        const float* __restrict__ bias, unsigned short* __restrict__ out) {
    __shared__ unsigned short At[2][128 * 64];
    __shared__ unsigned short Bt[2][128 * 64];
    const int m0 = blockIdx.y * 128;
    const int n0 = blockIdx.x * 128;
    const int tid = threadIdx.x;
    const int w = tid >> 6, l = tid & 63;
    const int wm = w >> 1, wn = w & 1;
    const int fr = l & 15, fq = l >> 4;

    const int ra = tid >> 1, hh = tid & 1;
    int mA = m0 + ra; if (mA > MROWS - 1) mA = MROWS - 1;
    const int tA = mA >> 3, bA = mA & 7;

    f32x4 acc[4][4] = {};
    const int NT = KTOT / 64;

    {
        const float* src = in + (size_t)(bA * CIN + 0) * LEN
                              + (size_t)tA * CSTRIDE + 0 + hh * 32;
        #pragma unroll
        for (int cc = 0; cc < 4; ++cc) {
            float4 f0 = reinterpret_cast<const float4*>(src)[cc * 2];
            float4 f1 = reinterpret_cast<const float4*>(src)[cc * 2 + 1];
            bf16x8 v;
            v[0] = bfc(f0.x); v[1] = bfc(f0.y); v[2] = bfc(f0.z); v[3] = bfc(f0.w);
            v[4] = bfc(f1.x); v[5] = bfc(f1.y); v[6] = bfc(f1.z); v[7] = bfc(f1.w);
            const int c = hh * 4 + cc, s = c ^ (ra & 7);
            *reinterpret_cast<bf16x8*>(&At[0][ra * 64 + s * 8]) = v;
        }
        #pragma unroll
        for (int i = 0; i < 4; ++i) {
            const int rb = w * 32 + i * 8 + (l >> 3);
            const int s = l & 7, c = s ^ (rb & 7);
            load_lds16(wb + (size_t)(n0 + rb) * KTOT + 0 + c * 8,
                       &Bt[0][(w * 32 + i * 8) * 64]);
        }
    }
    __syncthreads();

    int cur = 0;
    for (int t = 0; t < NT; ++t) {
        const int nxt = cur ^ 1;
        float4 fA[8];
        const bool more = (t + 1 < NT);
        if (more) {
            const int k0 = (t + 1) * 64;
            const int ci = k0 / KERN, kr = k0 - ci * KERN;
            const float* src = in + (size_t)(bA * CIN + ci) * LEN
                                  + (size_t)tA * CSTRIDE + kr + hh * 32;
            #pragma unroll
            for (int v = 0; v < 8; ++v)
                fA[v] = reinterpret_cast<const float4*>(src)[v];
            #pragma unroll
            for (int i = 0; i < 4; ++i) {
                const int rb = w * 32 + i * 8 + (l >> 3);
                const int s = l & 7, c = s ^ (rb & 7);
                load_lds16(wb + (size_t)(n0 + rb) * KTOT + k0 + c * 8,
                           &Bt[nxt][(w * 32 + i * 8) * 64]);
            }
        }
        #pragma unroll
        for (int ks = 0; ks < 2; ++ks) {
            bf16x8 af[4], bfg[4];
            #pragma unroll
            for (int mf = 0; mf < 4; ++mf) {
                const int rA = wm * 64 + mf * 16 + fr;
                const int cw = ks * 4 + fq, s = cw ^ (rA & 7);
                af[mf] = *reinterpret_cast<const bf16x8*>(&At[cur][rA * 64 + s * 8]);
            }
            #pragma unroll
            for (int nf = 0; nf < 4; ++nf) {
                const int rB = wn * 64 + nf * 16 + fr;
                const int cw = ks * 4 + fq, s = cw ^ (rB & 7);
                bfg[nf] = *reinterpret_cast<const bf16x8*>(&Bt[cur][rB * 64 + s * 8]);
            }
            #pragma unroll
            for (int mf = 0; mf < 4; ++mf)
                #pragma unroll
                for (int nf = 0; nf < 4; ++nf)
                    acc[mf][nf] = __builtin_amdgcn_mfma_f32_16x16x32_bf16(
                        af[mf], bfg[nf], acc[mf][nf], 0, 0, 0);
        }
        if (more) {
            #pragma unroll
            for (int cc = 0; cc < 4; ++cc) {
                float4 f0 = fA[cc * 2], f1 = fA[cc * 2 + 1];
                bf16x8 v;
                v[0] = bfc(f0.x); v[1] = bfc(f0.y); v[2] = bfc(f0.z); v[3] = bfc(f0.w);
                v[4] = bfc(f1.x); v[5] = bfc(f1.y); v[6] = bfc(f1.z); v[7] = bfc(f1.w);
                const int c = hh * 4 + cc, s = c ^ (ra & 7);
                *reinterpret_cast<bf16x8*>(&At[nxt][ra * 64 + s * 8]) = v;
            }
        }
        __syncthreads();
        cur = nxt;
    }

    #pragma unroll
    for (int nf = 0; nf < 4; ++nf) {
        const int n = n0 + wn * 64 + nf * 16 + fr;
        const float bv = bias[n];
        #pragma unroll
        for (int mf = 0; mf < 4; ++mf) {
            #pragma unroll
            for (int i = 0; i < 4; ++i) {
                const int m = m0 + wm * 64 + mf * 16 + fq * 4 + i;
                if (m < MROWS)
                    out[(size_t)m * COUT + n] =
                        (unsigned short)bfc(acc[mf][nf][i] + bv);
            }
        }
    }
}

// ---------------------------------------------------------------------------
// gi projection MFMA (unchanged from round 4)
// ---------------------------------------------------------------------------
__global__ __launch_bounds__(256, 2) void proj_mfma_k(
        const unsigned short* __restrict__ A, const unsigned short* __restrict__ wb,
        const float* __restrict__ bias, float* __restrict__ out) {
    __shared__ unsigned short At[2][128 * 64];
    __shared__ unsigned short Bt[2][128 * 64];
    const int m0 = blockIdx.y * 128;
    const int n0 = blockIdx.x * 128;
    const int tid = threadIdx.x;
    const int w = tid >> 6, l = tid & 63;
    const int wm = w >> 1, wn = w & 1;
    const int fr = l & 15, fq = l >> 4;

    f32x4 acc[4][4] = {};
    const int NT = COUT / 64;

    auto stage = [&](int buf, int k0) {
        #pragma unroll
        for (int i = 0; i < 4; ++i) {
            const int r = w * 32 + i * 8 + (l >> 3);
            const int s = l & 7, c = s ^ (r & 7);
            int mA = m0 + r; if (mA > MROWS - 1) mA = MROWS - 1;
            load_lds16(A + (size_t)mA * COUT + k0 + c * 8,
                       &At[buf][(w * 32 + i * 8) * 64]);
            load_lds16(wb + (size_t)(n0 + r) * COUT + k0 + c * 8,
                       &Bt[buf][(w * 32 + i * 8) * 64]);
        }
    };

    stage(0, 0);
    __syncthreads();
    int cur = 0;
    for (int t = 0; t < NT; ++t) {
        const int nxt = cur ^ 1;
        if (t + 1 < NT) stage(nxt, (t + 1) * 64);
        #pragma unroll
        for (int ks = 0; ks < 2; ++ks) {
            bf16x8 af[4], bfg[4];
            #pragma unroll
            for (int mf = 0; mf < 4; ++mf) {
                const int rA = wm * 64 + mf * 16 + fr;
                const int cw = ks * 4 + fq, s = cw ^ (rA & 7);
                af[mf] = *reinterpret_cast<const bf16x8*>(&At[cur][rA * 64 + s * 8]);
            }
            #pragma unroll
            for (int nf = 0; nf < 4; ++nf) {
                const int rB = wn * 64 + nf * 16 + fr;
                const int cw = ks * 4 + fq, s = cw ^ (rB & 7);
                bfg[nf] = *reinterpret_cast<const bf16x8*>(&Bt[cur][rB * 64 + s * 8]);
            }
            #pragma unroll
            for (int mf = 0; mf < 4; ++mf)
                #pragma unroll
                for (int nf = 0; nf < 4; ++nf)
                    acc[mf][nf] = __builtin_amdgcn_mfma_f32_16x16x32_bf16(
                        af[mf], bfg[nf], acc[mf][nf], 0, 0, 0);
        }
        __syncthreads();
        cur = nxt;
    }

    #pragma unroll
    for (int nf = 0; nf < 4; ++nf) {
        const int n = n0 + wn * 64 + nf * 16 + fr;
        const float bv = bias[n];
        #pragma unroll
        for (int mf = 0; mf < 4; ++mf) {
            #pragma unroll
            for (int i = 0; i < 4; ++i) {
                const int m = m0 + wm * 64 + mf * 16 + fq * 4 + i;
                if (m < MROWS)
                    out[(size_t)m * 1536 + n] = acc[mf][nf][i] + bv;
            }
        }
    }
}

// ---------------------------------------------------------------------------
// GRU scan, round 7. 8 teams x 4 slice-blocks, 1024 threads/block (16 waves).
// Wave wv: row-group rg=wv&7 (16 rows), k-half kh=wv>>3; lane: row r=l&15,
// 64-k chunk ck=l>>4 -> 96 half2 weights/thread (fits 128 VGPRs, no AGPR
// moves). k-reduce: 2 shfl_xor within wave + p_lds pair (stride 7, conflict-
// free) across the kh pair. hh2 padded (+4 half2 per 32) -> chunk g reads at
// bank 4g: conflict-free b128. Roles after B1: waves 0-1 gates+publish,
// waves 2-4 poll CONCURRENTLY (RT overlaps gate math). Exchange = round-3/4
// proven protocol: one relaxed agent-scope store per packed {epoch|2xfp16}
// word, direct relaxed agent poll, parity double-buffer (no overwrite before
// every consumer of that parity polled the previous epoch; exact-match safe).
// ---------------------------------------------------------------------------
__global__ __launch_bounds__(1024, 4) void gru_scan_k(
        const float* __restrict__ gi, const float* __restrict__ w_hh,
        const float* __restrict__ b_hh, const float* __restrict__ hidden,
        float* __restrict__ out, unsigned long long* __restrict__ h_ex) {
    const int bid = blockIdx.x;
    const int b   = bid & 7;           // team/batch
    const int isl = bid >> 3;          // slice 0..3
    const int tid = threadIdx.x;
    const int wv  = tid >> 6;          // wave 0..15
    const int l   = tid & 63;
    const int r   = l & 15;            // row within wave's 16
    const int ck  = l >> 4;            // 64-k chunk within the k-half
    const int rg  = wv & 7;            // row group 0..7
    const int kh  = wv >> 3;           // k half 0..1
    const int row = rg * 16 + r;       // block-row 0..127
    const int j   = isl * 128 + row;   // owned h row for matvec
    const int g8  = kh * 4 + ck;       // hh2 pad-group 0..7

    __shared__ __align__(16) __half2 hh2[2][288];   // 8 x (32+4) per parity
    __shared__ float p_lds[128 * 7];                // [row][3 gates x 2 kh], stride 7

    // weights: 3 gates x 64 k of row j -> 96 half2 VGPRs
    __half2 wreg[3][32];
    #pragma unroll
    for (int m = 0; m < 3; ++m) {
        const float* wp = w_hh + (size_t)(j + m * 512) * HID + kh * 256 + ck * 64;
        #pragma unroll
        for (int kk = 0; kk < 16; ++kk) {
            float4 v = reinterpret_cast<const float4*>(wp)[kk];
            wreg[m][2 * kk]     = __halves2half2(__float2half_rn(v.x), __float2half_rn(v.y));
            wreg[m][2 * kk + 1] = __halves2half2(__float2half_rn(v.z), __float2half_rn(v.w));
        }
    }

    const int jg = isl * 128 + (tid & 127);   // gate row (tid<128 only)
    float bhr = 0.f, bhz = 0.f, bhn = 0.f, hprev = 0.f;
    float gir = 0.f, giz = 0.f, gin = 0.f;
    if (tid < 128) {
        bhr = b_hh[jg]; bhz = b_hh[jg + 512]; bhn = b_hh[jg + 1024];
        hprev = hidden[b * HID + jg];
        gir = gi[(size_t)b * 1536 + jg];
        giz = gi[(size_t)b * 1536 + jg + 512];
        gin = gi[(size_t)b * 1536 + jg + 1024];
    }
    if (tid < 256) {
        __half2 h2 = __halves2half2(__float2half(hidden[b * HID + 2 * tid]),
                                    __float2half(hidden[b * HID + 2 * tid + 1]));
        hh2[0][(tid >> 5) * 36 + (tid & 31)] = h2;
    }
    __syncthreads();

    for (int t = 0; t < TSTEPS; ++t) {
        const bool more = (t + 1 < TSTEPS);
        // matvec over own 64-k chunk: 96 dot2, conflict-free b128 broadcasts
        const H2x4* hv4 = reinterpret_cast<const H2x4*>(&hh2[t & 1][g8 * 36]);
        float a0 = 0, a1 = 0, a2 = 0, c0 = 0, c1 = 0, c2 = 0;
        #pragma unroll
        for (int kk = 0; kk < 8; ++kk) {
            H2x4 h4 = hv4[kk];
            a0 = dot2f(wreg[0][4 * kk + 0], h4.x, a0);
            a1 = dot2f(wreg[1][4 * kk + 0], h4.x, a1);
            a2 = dot2f(wreg[2][4 * kk + 0], h4.x, a2);
            c0 = dot2f(wreg[0][4 * kk + 1], h4.y, c0);
            c1 = dot2f(wreg[1][4 * kk + 1], h4.y, c1);
            c2 = dot2f(wreg[2][4 * kk + 1], h4.y, c2);
            a0 = dot2f(wreg[0][4 * kk + 2], h4.z, a0);
            a1 = dot2f(wreg[1][4 * kk + 2], h4.z, a1);
            a2 = dot2f(wreg[2][4 * kk + 2], h4.z, a2);
            c0 = dot2f(wreg[0][4 * kk + 3], h4.w, c0);
            c1 = dot2f(wreg[1][4 * kk + 3], h4.w, c1);
            c2 = dot2f(wreg[2][4 * kk + 3], h4.w, c2);
        }
        float s0 = a0 + c0, s1 = a1 + c1, s2 = a2 + c2;
        s0 += __shfl_xor(s0, 16); s0 += __shfl_xor(s0, 32);
        s1 += __shfl_xor(s1, 16); s1 += __shfl_xor(s1, 32);
        s2 += __shfl_xor(s2, 16); s2 += __shfl_xor(s2, 32);
        if (l < 16) {   // one lane per (row, kh); stride 7: conflict-free
            p_lds[row * 7 + 0 + kh] = s0;
            p_lds[row * 7 + 2 + kh] = s1;
            p_lds[row * 7 + 4 + kh] = s2;
        }
        __syncthreads();   // B1

        if (tid < 128) {
            // gates (waves 0-1) — runs concurrently with the poll waves
            const float* pp = &p_lds[tid * 7];
            const float ghr = pp[0] + pp[1] + bhr;
            const float ghz = pp[2] + pp[3] + bhz;
            const float ghn = pp[4] + pp[5] + bhn;
            const float rr = 1.f / (1.f + __expf(-(gir + ghr)));
            const float zz = 1.f / (1.f + __expf(-(giz + ghz)));
            const float nx = gin + rr * ghn;
            const float nn = 1.f - 2.f / (__expf(2.f * nx) + 1.f);   // tanh
            const float hnew = (1.f - zz) * nn + zz * hprev;
            hprev = hnew;
            const float hother = __shfl_xor(hnew, 1);
            const __half2 h2 = __halves2half2(__float2half(hnew),
                                              __float2half(hother));
            if (more && !(tid & 1)) {
                const unsigned long long v =
                    ((unsigned long long)(unsigned)(t + 1) << 32) |
                    (unsigned long long)__builtin_bit_cast(unsigned, h2);
                const int w0 = isl * 64 + (tid >> 1);
                __hip_atomic_store(
                    h_ex + (size_t)(((t + 1) & 1) * BATCH + b) * 256 + w0,
                    v, __ATOMIC_RELAXED, __HIP_MEMORY_SCOPE_AGENT);
                hh2[(t + 1) & 1][(w0 >> 5) * 36 + (w0 & 31)] = h2;   // own slice
            }
            out[(size_t)(t * BATCH + b) * HID + jg] = hnew;
            if (more) {   // prefetch gi[t+1]; hidden under B2+matvec+B1
                const float* gp = gi + (size_t)((t + 1) * BATCH + b) * 1536 + jg;
                gir = gp[0]; giz = gp[512]; gin = gp[1024];
            }
        } else if (tid < 320 && more) {
            // poll waves 2-4: one remote word each (skip own slice)
            const int i = tid - 128;
            const int w0 = i + ((i >= isl * 64) ? 64 : 0);
            const unsigned long long* src =
                h_ex + (size_t)(((t + 1) & 1) * BATCH + b) * 256 + w0;
            unsigned long long v;
            do {
                v = __hip_atomic_load(src, __ATOMIC_RELAXED,
                                      __HIP_MEMORY_SCOPE_AGENT);
            } while ((unsigned)(v >> 32) != (unsigned)(t + 1));
            hh2[(t + 1) & 1][(w0 >> 5) * 36 + (w0 & 31)] =
                __builtin_bit_cast(__half2, (unsigned)(v & 0xffffffffu));
        }
        __syncthreads();   // B2
    }
    if (tid < 128)
        out[(size_t)TSTEPS * BATCH * HID + b * HID + jg] = hprev;
}

extern "C" void kernel_launch(void* const* d_in, const int* in_sizes, int n_in,
                              void* d_out, int out_size, void* d_ws, size_t ws_size,
                              hipStream_t stream) {
    (void)in_sizes; (void)n_in; (void)out_size; (void)ws_size;
    const float* input  = (const float*)d_in[0];
    const float* hidden = (const float*)d_in[1];
    const float* conv_w = (const float*)d_in[2];
    const float* conv_b = (const float*)d_in[3];
    const float* w_ih   = (const float*)d_in[4];
    const float* w_hh   = (const float*)d_in[5];
    const float* b_ih   = (const float*)d_in[6];
    const float* b_hh   = (const float*)d_in[7];
    float* out = (float*)d_out;

    char* ws = (char*)d_ws;
    float*          gi       = (float*)ws;                          // 50,085,888 B
    unsigned short* conv_out = (unsigned short*)(ws + 50085888);    //  8,347,648 B
    unsigned short* w_bf     = (unsigned short*)(ws + 58433536);    // 12,582,912 B
    unsigned short* wih_bf   = (unsigned short*)(ws + 71016448);    //  1,572,864 B
    unsigned long long* h_ex = (unsigned long long*)(ws + 72589312);//     32,768 B

    f2bf_k<<<2048, 256, 0, stream>>>(conv_w, w_bf, KTOT * COUT / 4);
    f2bf_k<<<768, 256, 0, stream>>>(w_ih, wih_bf, 1536 * COUT / 4);

    dim3 cgrid(4, 64);
    conv_mfma_k<<<cgrid, 256, 0, stream>>>(input, w_bf, conv_b, conv_out);

    dim3 pgrid(12, 64);
    proj_mfma_k<<<pgrid, 256, 0, stream>>>(conv_out, wih_bf, b_ih, gi);

    // reset exchange epochs each launch (replays don't re-poison d_ws)
    hipMemsetAsync(h_ex, 0, 32768, stream);

    gru_scan_k<<<32, 1024, 0, stream>>>(gi, w_hh, b_hh, hidden, out, h_ex);
}